// Round 7
// baseline (1301.390 us; speedup 1.0000x reference)
//
#include <hip/hip_runtime.h>
#include <math.h>

// ---------------------------------------------------------------------------
// GraphAutoEncoder forward on MI355X. Round 6:
//   - prop gather unrolled x4, dual accumulators (latency hiding; round-5
//     counters showed VALUBusy 13%, 16 VGPR -> latency-bound)
//   - GCN2 combine passes fused into GEMM epilogues (EPI=3 f32, EPI=4 hi/lo)
//   - fused single-pass GAT, MFMA split-bf16 GEMMs unchanged
// ---------------------------------------------------------------------------

static constexpr int HEADS = 4;

typedef __attribute__((ext_vector_type(8))) short short8;
typedef __attribute__((ext_vector_type(4))) float f32x4;

__device__ __forceinline__ unsigned short f32_to_bf16(float x) {
  unsigned int u = __float_as_uint(x);
  u = (u + 0x7FFF + ((u >> 16) & 1)) >> 16;   // RNE
  return (unsigned short)u;
}
__device__ __forceinline__ float bf16_to_f32(unsigned short h) {
  return __uint_as_float(((unsigned int)h) << 16);
}

// ---------------- CSR build ----------------

__global__ void deg_kernel(const int* __restrict__ ei, int* __restrict__ deg, int E) {
  int i = blockIdx.x * blockDim.x + threadIdx.x;
  int stride = gridDim.x * blockDim.x;
  for (; i < E; i += stride) atomicAdd(&deg[ei[E + i]], 1);
}

__global__ void dinv_kernel(const int* __restrict__ deg, float* __restrict__ dinv, int N) {
  int i = blockIdx.x * blockDim.x + threadIdx.x;
  if (i < N) dinv[i] = rsqrtf((float)(deg[i] + 1));  // +1 self-loop
}

__global__ __launch_bounds__(256) void scan_block_kernel(const int* __restrict__ in,
                                                         int* __restrict__ out,
                                                         int* __restrict__ bsum, int n) {
  __shared__ int lds[256];
  const int base = blockIdx.x * 2048;
  const int tid = threadIdx.x;
  int v[8];
  int s = 0;
#pragma unroll
  for (int k = 0; k < 8; ++k) {
    int idx = base + tid * 8 + k;
    v[k] = (idx < n) ? in[idx] : 0;
    s += v[k];
  }
  lds[tid] = s;
  __syncthreads();
  for (int off = 1; off < 256; off <<= 1) {
    int t = (tid >= off) ? lds[tid - off] : 0;
    __syncthreads();
    lds[tid] += t;
    __syncthreads();
  }
  int run = (tid > 0) ? lds[tid - 1] : 0;
#pragma unroll
  for (int k = 0; k < 8; ++k) {
    int idx = base + tid * 8 + k;
    run += v[k];
    if (idx < n) out[idx] = run;
  }
  if (tid == 255) bsum[blockIdx.x] = lds[255];
}

__global__ void scan_small_kernel(int* bsum, int nb) {
  if (threadIdx.x == 0 && blockIdx.x == 0) {
    int run = 0;
    for (int i = 0; i < nb; ++i) { int t = bsum[i]; bsum[i] = run; run += t; }
  }
}

__global__ __launch_bounds__(256) void scan_add_kernel(int* __restrict__ out,
                                                       const int* __restrict__ bsum, int n) {
  int idx = blockIdx.x * 2048 + threadIdx.x;
  const int add = bsum[blockIdx.x];
#pragma unroll
  for (int k = 0; k < 8; ++k, idx += 256)
    if (idx < n) out[idx] += add;
}

__global__ void fill_csr_kernel(const int* __restrict__ ei, const float* __restrict__ dinv,
                                const int* __restrict__ rowptr, int* __restrict__ fill,
                                int* __restrict__ cols, float* __restrict__ vals, int E) {
  int e = blockIdx.x * blockDim.x + threadIdx.x;
  int stride = gridDim.x * blockDim.x;
  for (; e < E; e += stride) {
    int s = ei[e], t = ei[E + e];
    int pos = rowptr[t] + atomicAdd(&fill[t], 1);
    cols[pos] = s;
    vals[pos] = dinv[s] * dinv[t];
  }
}

// ---------------- propagation (CSR gather, float4, unroll-4) ----------------
// EPI: 0 none | 1 +bias | 2 relu(+bias) | 3 0.5*acc+0.5*x0
// OUT: 0 f32 only | 1 hi/lo bf16 planes only | 2 both
template <int D, int EPI, int OUT>
__global__ __launch_bounds__(256) void prop_csr_kernel(
    const float4* __restrict__ h, const int* __restrict__ rowptr,
    const int* __restrict__ cols, const float* __restrict__ vals,
    const float* __restrict__ dinv, const float* __restrict__ bx,
    float4* __restrict__ out, ushort4* __restrict__ hi, ushort4* __restrict__ lo,
    int N) {
  constexpr int TPN = D / 4;
  constexpr int NPB = 256 / TPN;
  const int node = blockIdx.x * NPB + threadIdx.x / TPN;
  const int q = threadIdx.x % TPN;
  if (node >= N) return;
  const int start = rowptr[node], end = rowptr[node + 1];
  float4 acc = make_float4(0.f, 0.f, 0.f, 0.f);
  float4 acc2 = make_float4(0.f, 0.f, 0.f, 0.f);
  int j = start;
  for (; j + 3 < end; j += 4) {
    const int c0 = cols[j], c1 = cols[j + 1], c2 = cols[j + 2], c3 = cols[j + 3];
    const float v0 = vals[j], v1 = vals[j + 1], v2 = vals[j + 2], v3 = vals[j + 3];
    const float4 a0 = h[(long long)c0 * TPN + q];
    const float4 a1 = h[(long long)c1 * TPN + q];
    const float4 a2 = h[(long long)c2 * TPN + q];
    const float4 a3 = h[(long long)c3 * TPN + q];
    acc.x += v0 * a0.x + v1 * a1.x;  acc2.x += v2 * a2.x + v3 * a3.x;
    acc.y += v0 * a0.y + v1 * a1.y;  acc2.y += v2 * a2.y + v3 * a3.y;
    acc.z += v0 * a0.z + v1 * a1.z;  acc2.z += v2 * a2.z + v3 * a3.z;
    acc.w += v0 * a0.w + v1 * a1.w;  acc2.w += v2 * a2.w + v3 * a3.w;
  }
  for (; j < end; ++j) {
    const float v = vals[j];
    const float4 a = h[(long long)cols[j] * TPN + q];
    acc.x += v * a.x; acc.y += v * a.y; acc.z += v * a.z; acc.w += v * a.w;
  }
  {
    const float di = dinv[node];
    const float sv = di * di;
    const float4 a = h[(long long)node * TPN + q];
    acc2.x += sv * a.x; acc2.y += sv * a.y; acc2.z += sv * a.z; acc2.w += sv * a.w;
  }
  acc.x += acc2.x; acc.y += acc2.y; acc.z += acc2.z; acc.w += acc2.w;
  float4 r;
  if (EPI == 0) {
    r = acc;
  } else if (EPI == 1 || EPI == 2) {
    float4 b = ((const float4*)bx)[q];
    r.x = acc.x + b.x; r.y = acc.y + b.y; r.z = acc.z + b.z; r.w = acc.w + b.w;
    if (EPI == 2) {
      r.x = fmaxf(r.x, 0.f); r.y = fmaxf(r.y, 0.f);
      r.z = fmaxf(r.z, 0.f); r.w = fmaxf(r.w, 0.f);
    }
  } else {
    float4 x0 = ((const float4*)bx)[(long long)node * TPN + q];
    r.x = 0.5f * (acc.x + x0.x); r.y = 0.5f * (acc.y + x0.y);
    r.z = 0.5f * (acc.z + x0.z); r.w = 0.5f * (acc.w + x0.w);
  }
  if (OUT != 1) out[(long long)node * TPN + q] = r;
  if (OUT >= 1) {
    ushort4 h4, l4;
    h4.x = f32_to_bf16(r.x); l4.x = f32_to_bf16(r.x - bf16_to_f32(h4.x));
    h4.y = f32_to_bf16(r.y); l4.y = f32_to_bf16(r.y - bf16_to_f32(h4.y));
    h4.z = f32_to_bf16(r.z); l4.z = f32_to_bf16(r.z - bf16_to_f32(h4.z));
    h4.w = f32_to_bf16(r.w); l4.w = f32_to_bf16(r.w - bf16_to_f32(h4.w));
    hi[(long long)node * TPN + q] = h4;
    lo[(long long)node * TPN + q] = l4;
  }
}

// ---------------- split-bf16 conversion (standalone, 2 uses) ----------------
__global__ void conv_hilo_kernel(const float* __restrict__ in, unsigned short* __restrict__ hi,
                                 unsigned short* __restrict__ lo, int N, int K, int Kp) {
  const long long total = (long long)N * (Kp / 4);
  long long i = (long long)blockIdx.x * blockDim.x + threadIdx.x;
  const long long stride = (long long)gridDim.x * blockDim.x;
  const int q = Kp / 4;
  for (; i < total; i += stride) {
    int r = (int)(i / q);
    int col = (int)(i % q) * 4;
    ushort4 h4 = make_ushort4(0, 0, 0, 0), l4 = make_ushort4(0, 0, 0, 0);
    if (col < K) {
      float4 v = *(const float4*)(in + (long long)r * K + col);
      h4.x = f32_to_bf16(v.x); l4.x = f32_to_bf16(v.x - bf16_to_f32(h4.x));
      h4.y = f32_to_bf16(v.y); l4.y = f32_to_bf16(v.y - bf16_to_f32(h4.y));
      h4.z = f32_to_bf16(v.z); l4.z = f32_to_bf16(v.z - bf16_to_f32(h4.z));
      h4.w = f32_to_bf16(v.w); l4.w = f32_to_bf16(v.w - bf16_to_f32(h4.w));
    }
    *(ushort4*)(hi + (long long)r * Kp + col) = h4;
    *(ushort4*)(lo + (long long)r * Kp + col) = l4;
  }
}

// ---------------- weight packing (fragment order) ----------------
// lane l holds B[k = 64*chunk + 32*s + 8*(l>>4) + j][col = 16*t + (l&15)]
__global__ void pack_w_kernel(const float* __restrict__ W, unsigned short* __restrict__ hi,
                              unsigned short* __restrict__ lo, int K, int M) {
  int i = blockIdx.x * blockDim.x + threadIdx.x;
  int stride = gridDim.x * blockDim.x;
  const int MT = M >> 4;
  for (; i < K * M; i += stride) {
    int k = i / M, m = i % M;
    float v = W[i];
    unsigned short h = f32_to_bf16(v);
    unsigned short l = f32_to_bf16(v - bf16_to_f32(h));
    int chunk = k >> 6, kin = k & 63;
    int s = (kin >> 5) & 1, kin2 = kin & 31;
    int lane = ((kin2 >> 3) << 4) | (m & 15);
    int j = kin2 & 7, t = m >> 4;
    long long idx = ((((long long)(chunk * MT + t) * 2 + s) * 64 + lane) * 8 + j);
    hi[idx] = h;
    lo[idx] = l;
  }
}

// ---------------- MFMA GEMM (split-bf16, 3 products) ----------------
// EPI: 0 none | 2 bias+relu | 3 C=relu(c1*aux+c2*acc) | 4 hi/lo=split(relu(c1*aux+c2*acc))
template <int MT, int EPI>
__global__ __launch_bounds__(256) void gemm_mfma_kernel(
    const unsigned short* __restrict__ Ahi, const unsigned short* __restrict__ Alo,
    const unsigned short* __restrict__ Phi, const unsigned short* __restrict__ Plo,
    const float* __restrict__ bias, const float* __restrict__ aux,
    float* __restrict__ C, unsigned short* __restrict__ oHi, unsigned short* __restrict__ oLo,
    float c1, float c2, int N, int Kp) {
  constexpr int M = MT * 16;
  constexpr int chunk_elems = M * 64;
  __shared__ unsigned short lds[2 * chunk_elems];
  const int tid = threadIdx.x;
  const int w = tid >> 6, l = tid & 63;
  const int lr = l & 15, lh = l >> 4;
  const int rowbase = blockIdx.x * 128 + w * 32;
  int r0 = rowbase + lr;      if (r0 >= N) r0 = N - 1;
  int r1 = rowbase + 16 + lr; if (r1 >= N) r1 = N - 1;

  f32x4 acc[2][MT] = {};
  unsigned short* ldsHi = lds;
  unsigned short* ldsLo = lds + chunk_elems;
  const int nchunks = Kp >> 6;
  const int n16 = chunk_elems / 8;

  for (int c = 0; c < nchunks; ++c) {
    const uint4* srcH = (const uint4*)(Phi + (long long)c * chunk_elems);
    const uint4* srcL = (const uint4*)(Plo + (long long)c * chunk_elems);
    uint4* dH = (uint4*)ldsHi;
    uint4* dL = (uint4*)ldsLo;
    __syncthreads();
    for (int i = tid; i < n16; i += 256) { dH[i] = srcH[i]; dL[i] = srcL[i]; }
    __syncthreads();
#pragma unroll
    for (int s = 0; s < 2; ++s) {
      const long long abase = (long long)c * 64 + s * 32 + lh * 8;
      short8 a0h = *(const short8*)(Ahi + (long long)r0 * Kp + abase);
      short8 a0l = *(const short8*)(Alo + (long long)r0 * Kp + abase);
      short8 a1h = *(const short8*)(Ahi + (long long)r1 * Kp + abase);
      short8 a1l = *(const short8*)(Alo + (long long)r1 * Kp + abase);
#pragma unroll
      for (int t = 0; t < MT; ++t) {
        const int boff = ((t * 2 + s) * 64 + l) * 8;
        short8 bh = *(const short8*)(ldsHi + boff);
        short8 bl = *(const short8*)(ldsLo + boff);
        acc[0][t] = __builtin_amdgcn_mfma_f32_16x16x32_bf16(a0h, bh, acc[0][t], 0, 0, 0);
        acc[0][t] = __builtin_amdgcn_mfma_f32_16x16x32_bf16(a0h, bl, acc[0][t], 0, 0, 0);
        acc[0][t] = __builtin_amdgcn_mfma_f32_16x16x32_bf16(a0l, bh, acc[0][t], 0, 0, 0);
        acc[1][t] = __builtin_amdgcn_mfma_f32_16x16x32_bf16(a1h, bh, acc[1][t], 0, 0, 0);
        acc[1][t] = __builtin_amdgcn_mfma_f32_16x16x32_bf16(a1h, bl, acc[1][t], 0, 0, 0);
        acc[1][t] = __builtin_amdgcn_mfma_f32_16x16x32_bf16(a1l, bh, acc[1][t], 0, 0, 0);
      }
    }
  }
#pragma unroll
  for (int rt = 0; rt < 2; ++rt) {
#pragma unroll
    for (int t = 0; t < MT; ++t) {
      const int col = t * 16 + lr;
      float b = (EPI == 2) ? bias[col] : 0.f;
#pragma unroll
      for (int j = 0; j < 4; ++j) {
        int row = rowbase + rt * 16 + lh * 4 + j;
        if (row < N) {
          float v;
          if (EPI == 3 || EPI == 4) {
            v = fmaxf(c1 * aux[(long long)row * M + col] + c2 * acc[rt][t][j], 0.f);
          } else {
            v = acc[rt][t][j] + b;
            if (EPI == 2) v = fmaxf(v, 0.f);
          }
          if (EPI == 4) {
            unsigned short hh = f32_to_bf16(v);
            unsigned short ll = f32_to_bf16(v - bf16_to_f32(hh));
            oHi[(long long)row * M + col] = hh;
            oLo[(long long)row * M + col] = ll;
          } else {
            C[(long long)row * M + col] = v;
          }
        }
      }
    }
  }
}

// ---------------- fused GATv2 (online softmax, one CSR pass) ----------------
__global__ __launch_bounds__(256) void gat_fused_kernel(
    const float2* __restrict__ xl, const float2* __restrict__ xr,
    const float* __restrict__ att, const int* __restrict__ rowptr,
    const int* __restrict__ cols, const float* __restrict__ bg,
    float2* __restrict__ outv, int N) {
  const int node = blockIdx.x * 4 + (threadIdx.x >> 6);
  if (node >= N) return;
  const int lane = threadIdx.x & 63;
  const float2 xrv = xr[(long long)node * 64 + lane];
  const float2 av = ((const float2*)att)[lane];
  float m = -1e30f, s = 0.f;
  float accx = 0.f, accy = 0.f;
  const int start = rowptr[node], end = rowptr[node + 1];
  for (int j = start; j <= end; ++j) {
    const int col = (j < end) ? cols[j] : node;   // j==end: self-loop
    const float2 xlv = xl[(long long)col * 64 + lane];
    float tx = xlv.x + xrv.x, ty = xlv.y + xrv.y;
    tx = tx >= 0.f ? tx : 0.2f * tx;
    ty = ty >= 0.f ? ty : 0.2f * ty;
    float dot = av.x * tx + av.y * ty;
    dot += __shfl_xor(dot, 1);
    dot += __shfl_xor(dot, 2);
    dot += __shfl_xor(dot, 4);
    dot += __shfl_xor(dot, 8);   // 16-lane head group reduce
    const float mn = fmaxf(m, dot);
    const float scale = __expf(m - mn);
    const float p = __expf(dot - mn);
    s = s * scale + p;
    accx = accx * scale + p * xlv.x;
    accy = accy * scale + p * xlv.y;
    m = mn;
  }
  const float inv = 1.0f / (s + 1e-16f);
  const float2 b = ((const float2*)bg)[lane];
  float2 r;
  r.x = fmaxf(accx * inv + b.x, 0.f);
  r.y = fmaxf(accy * inv + b.y, 0.f);
  outv[(long long)node * 64 + lane] = r;
}

// ---------------------------------------------------------------------------

extern "C" void kernel_launch(void* const* d_in, const int* in_sizes, int n_in,
                              void* d_out, int out_size, void* d_ws, size_t ws_size,
                              hipStream_t stream) {
  const float* x  = (const float*)d_in[0];
  const int*   ei = (const int*)d_in[1];
  const float* W1 = (const float*)d_in[2];  const float* b1 = (const float*)d_in[3];
  const float* W2 = (const float*)d_in[4];  const float* b2 = (const float*)d_in[5];
  const float* W3 = (const float*)d_in[6];  const float* b3 = (const float*)d_in[7];
  const float* W4 = (const float*)d_in[8];  const float* b4 = (const float*)d_in[9];
  const float* Wl = (const float*)d_in[10]; const float* Wr = (const float*)d_in[11];
  const float* att= (const float*)d_in[12]; const float* bg = (const float*)d_in[13];
  const float* Wc1= (const float*)d_in[14];
  const float* W5 = (const float*)d_in[15]; const float* b5 = (const float*)d_in[16];
  const float* Wc2= (const float*)d_in[17];
  const float* Wo = (const float*)d_in[18]; const float* bo = (const float*)d_in[19];

  const int N = in_sizes[0] / 300;
  const int E = in_sizes[1] / 2;
  float* out = (float*)d_out;

  const float BETA = 0.04879016416943205f;
  const float OMB  = 1.0f - BETA;

  // ---- workspace carve-up ----
  float* wsf = (float*)d_ws;
  auto alloc = [&](long long nelem) {
    float* p = wsf; wsf += (nelem + 3) & ~3LL; return p;
  };
  float* dinv   = alloc(N);
  int*   rowptr = (int*)alloc(N + 1);
  int*   cols   = (int*)alloc(E);
  float* vals   = alloc(E);
  float* x1     = alloc((long long)N * 256);
  float* x2     = alloc((long long)N * 128);
  float* bufA   = alloc((long long)N * 256);
  float* bufB   = alloc((long long)N * 256);
  int*   bsum   = (int*)alloc(64);
  unsigned short* Ahi = (unsigned short*)alloc((long long)N * 160);  // N*320 ushorts
  unsigned short* Alo = (unsigned short*)alloc((long long)N * 160);
  struct WDesc { const float* W; int K, M; };
  WDesc wd[10] = {{W1,300,256},{W2,256,128},{W3,128,64},{W4,64,32},{Wl,32,128},
                  {Wr,32,128},{Wc1,128,128},{W5,128,256},{Wc2,256,256},{Wo,256,128}};
  long long woff[10], wtot = 0;
  int wkp[10];
  for (int i = 0; i < 10; ++i) {
    wkp[i] = (wd[i].K + 63) & ~63;
    woff[i] = wtot;
    wtot += 2LL * wkp[i] * wd[i].M;
  }
  unsigned short* warena = (unsigned short*)alloc(wtot / 2 + 4);
  // setup-only overlays on Ahi/Alo (dead until first conv/prop-hilo):
  int* deg  = (int*)Ahi;
  int* fill = (int*)Alo;

  auto convA = [&](const float* src, int K, int Kp) {
    long long total = (long long)N * (Kp / 4);
    int blocks = (int)(((total + 255) / 256 < 4096) ? (total + 255) / 256 : 4096);
    conv_hilo_kernel<<<blocks, 256, 0, stream>>>(src, Ahi, Alo, N, K, Kp);
  };
  const int gemm_grid = (N + 127) / 128;
  auto gemm = [&](int wi, const float* bias, const float* aux, float* C,
                  unsigned short* oHi, unsigned short* oLo, float c1, float c2,
                  int MT, int epi) {
    const unsigned short* Phi = warena + woff[wi];
    const unsigned short* Plo = Phi + (long long)wkp[wi] * wd[wi].M;
#define GEMM_CASE(MM, EE) \
    if (MT == MM && epi == EE) { gemm_mfma_kernel<MM,EE><<<gemm_grid, 256, 0, stream>>>( \
        Ahi, Alo, Phi, Plo, bias, aux, C, oHi, oLo, c1, c2, N, wkp[wi]); return; }
    GEMM_CASE(16,0) GEMM_CASE(16,2) GEMM_CASE(16,4)
    GEMM_CASE(8,0)  GEMM_CASE(8,3)
    GEMM_CASE(4,0)  GEMM_CASE(2,0)
#undef GEMM_CASE
  };
  ushort4* hi4 = (ushort4*)Ahi;
  ushort4* lo4 = (ushort4*)Alo;

  // ---- weight packing (once per launch) ----
  hipMemsetAsync(warena, 0, (size_t)wtot * sizeof(unsigned short), stream);
  for (int i = 0; i < 10; ++i) {
    unsigned short* Phi = warena + woff[i];
    unsigned short* Plo = Phi + (long long)wkp[i] * wd[i].M;
    int total = wd[i].K * wd[i].M;
    pack_w_kernel<<<(total + 255) / 256, 256, 0, stream>>>(wd[i].W, Phi, Plo, wd[i].K, wd[i].M);
  }

  // ---- CSR build ----
  hipMemsetAsync(deg, 0, (size_t)N * sizeof(int), stream);
  hipMemsetAsync(fill, 0, (size_t)N * sizeof(int), stream);
  hipMemsetAsync(rowptr, 0, sizeof(int), stream);
  deg_kernel<<<2048, 256, 0, stream>>>(ei, deg, E);
  dinv_kernel<<<(N + 255) / 256, 256, 0, stream>>>(deg, dinv, N);
  {
    int nb = (N + 2047) / 2048;
    scan_block_kernel<<<nb, 256, 0, stream>>>(deg, rowptr + 1, bsum, N);
    scan_small_kernel<<<1, 64, 0, stream>>>(bsum, nb);
    scan_add_kernel<<<nb, 256, 0, stream>>>(rowptr + 1, bsum, N);
  }
  fill_csr_kernel<<<2048, 256, 0, stream>>>(ei, dinv, rowptr, fill, cols, vals, E);

  // ---- layer 1: x1 = relu(prop(x@W1)+b1)  [+ hilo planes] ----
  convA(x, 300, 320);
  gemm(0, nullptr, nullptr, bufA, nullptr, nullptr, 0, 0, 16, 0);
  prop_csr_kernel<256,2,2><<<(N + 3) / 4, 256, 0, stream>>>(
      (const float4*)bufA, rowptr, cols, vals, dinv, b1, (float4*)x1, hi4, lo4, N);

  // ---- layer 2: x2 [+ planes] ----
  gemm(1, nullptr, nullptr, bufA, nullptr, nullptr, 0, 0, 8, 0);
  prop_csr_kernel<128,2,2><<<(N + 7) / 8, 256, 0, stream>>>(
      (const float4*)bufA, rowptr, cols, vals, dinv, b2, (float4*)x2, hi4, lo4, N);

  // ---- layer 3: planes only ----
  gemm(2, nullptr, nullptr, bufA, nullptr, nullptr, 0, 0, 4, 0);
  prop_csr_kernel<64,2,1><<<(N + 15) / 16, 256, 0, stream>>>(
      (const float4*)bufA, rowptr, cols, vals, dinv, b3, nullptr, hi4, lo4, N);

  // ---- layer 4: f32 (D=32 pads via convA) ----
  gemm(3, nullptr, nullptr, bufA, nullptr, nullptr, 0, 0, 2, 0);
  prop_csr_kernel<32,2,0><<<(N + 31) / 32, 256, 0, stream>>>(
      (const float4*)bufA, rowptr, cols, vals, dinv, b4, (float4*)bufB, nullptr, nullptr, N);
  convA(bufB, 32, 64);

  // ---- GATv2 (fused single pass) ----
  gemm(4, nullptr, nullptr, bufA, nullptr, nullptr, 0, 0, 8, 0);  // xl
  gemm(5, nullptr, nullptr, bufB, nullptr, nullptr, 0, 0, 8, 0);  // xr
  gat_fused_kernel<<<(N + 3) / 4, 256, 0, stream>>>(
      (const float2*)bufA, (const float2*)bufB, att, rowptr, cols, bg, (float2*)bufB, N);
  // x3 (N x 128) in bufB

  // ---- GCN2 #1: h = 0.5*prop(x3)+0.5*x2; res = relu(OMB*h + BETA*h@Wc1) ----
  prop_csr_kernel<128,3,2><<<(N + 7) / 8, 256, 0, stream>>>(
      (const float4*)bufB, rowptr, cols, vals, dinv, x2, (float4*)bufA, hi4, lo4, N);
  gemm(6, nullptr, bufA, bufB, nullptr, nullptr, OMB, BETA, 8, 3);  // res in bufB

  // ---- W5 layer: relu(prop(res)@W5+b5) ----
  prop_csr_kernel<128,0,1><<<(N + 7) / 8, 256, 0, stream>>>(
      (const float4*)bufB, rowptr, cols, vals, dinv, nullptr, nullptr, hi4, lo4, N);
  gemm(7, b5, nullptr, bufB, nullptr, nullptr, 0, 0, 16, 2);        // (N x 256) in bufB

  // ---- GCN2 #2: h = 0.5*prop(.)+0.5*x1; planes = split(relu(OMB*h + BETA*h@Wc2)) ----
  prop_csr_kernel<256,3,2><<<(N + 3) / 4, 256, 0, stream>>>(
      (const float4*)bufB, rowptr, cols, vals, dinv, x1, (float4*)bufA, hi4, lo4, N);
  gemm(8, nullptr, bufA, nullptr, Ahi, Alo, OMB, BETA, 16, 4);      // planes direct

  // ---- final: prop(x@Wo) + bo ----
  gemm(9, nullptr, nullptr, bufB, nullptr, nullptr, 0, 0, 8, 0);    // (N x 128)
  prop_csr_kernel<128,1,0><<<(N + 7) / 8, 256, 0, stream>>>(
      (const float4*)bufB, rowptr, cols, vals, dinv, bo, (float4*)out, nullptr, nullptr, N);
}

// Round 8
// 954.795 us; speedup vs baseline: 1.3630x; 1.3630x over previous
//
#include <hip/hip_runtime.h>
#include <math.h>

// ---------------------------------------------------------------------------
// GraphAutoEncoder forward on MI355X. Round 8:
//   - ALL gathered feature arrays stored fp16 (accumulate f32): halves the
//     per-prop fabric traffic that bounds rounds 5-7 (480MB FETCH/dispatch)
//   - GEMM fp16 outputs staged via LDS -> coalesced 16B stores (avoids the
//     scattered 2B-store regression of round 7's EPI=4)
//   - prop loop back to round-5 unroll-2 (unroll-4 measured neutral/worse)
//   - GCN2 combines back to standalone vectorized kernels
//   - residuals x1/x2 stored fp16 (ws ~239MB < proven 244MB)
// ---------------------------------------------------------------------------

static constexpr int HEADS = 4;

typedef __attribute__((ext_vector_type(8))) short short8;
typedef __attribute__((ext_vector_type(4))) float f32x4;
typedef _Float16 hf2 __attribute__((ext_vector_type(2)));
typedef _Float16 hf4 __attribute__((ext_vector_type(4)));

__device__ __forceinline__ unsigned short f32_to_bf16(float x) {
  unsigned int u = __float_as_uint(x);
  u = (u + 0x7FFF + ((u >> 16) & 1)) >> 16;   // RNE
  return (unsigned short)u;
}
__device__ __forceinline__ float bf16_to_f32(unsigned short h) {
  return __uint_as_float(((unsigned int)h) << 16);
}

// ---------------- CSR build ----------------

__global__ void deg_kernel(const int* __restrict__ ei, int* __restrict__ deg, int E) {
  int i = blockIdx.x * blockDim.x + threadIdx.x;
  int stride = gridDim.x * blockDim.x;
  for (; i < E; i += stride) atomicAdd(&deg[ei[E + i]], 1);
}

__global__ void dinv_kernel(const int* __restrict__ deg, float* __restrict__ dinv, int N) {
  int i = blockIdx.x * blockDim.x + threadIdx.x;
  if (i < N) dinv[i] = rsqrtf((float)(deg[i] + 1));  // +1 self-loop
}

__global__ __launch_bounds__(256) void scan_block_kernel(const int* __restrict__ in,
                                                         int* __restrict__ out,
                                                         int* __restrict__ bsum, int n) {
  __shared__ int lds[256];
  const int base = blockIdx.x * 2048;
  const int tid = threadIdx.x;
  int v[8];
  int s = 0;
#pragma unroll
  for (int k = 0; k < 8; ++k) {
    int idx = base + tid * 8 + k;
    v[k] = (idx < n) ? in[idx] : 0;
    s += v[k];
  }
  lds[tid] = s;
  __syncthreads();
  for (int off = 1; off < 256; off <<= 1) {
    int t = (tid >= off) ? lds[tid - off] : 0;
    __syncthreads();
    lds[tid] += t;
    __syncthreads();
  }
  int run = (tid > 0) ? lds[tid - 1] : 0;
#pragma unroll
  for (int k = 0; k < 8; ++k) {
    int idx = base + tid * 8 + k;
    run += v[k];
    if (idx < n) out[idx] = run;
  }
  if (tid == 255) bsum[blockIdx.x] = lds[255];
}

__global__ void scan_small_kernel(int* bsum, int nb) {
  if (threadIdx.x == 0 && blockIdx.x == 0) {
    int run = 0;
    for (int i = 0; i < nb; ++i) { int t = bsum[i]; bsum[i] = run; run += t; }
  }
}

__global__ __launch_bounds__(256) void scan_add_kernel(int* __restrict__ out,
                                                       const int* __restrict__ bsum, int n) {
  int idx = blockIdx.x * 2048 + threadIdx.x;
  const int add = bsum[blockIdx.x];
#pragma unroll
  for (int k = 0; k < 8; ++k, idx += 256)
    if (idx < n) out[idx] += add;
}

__global__ void fill_csr_kernel(const int* __restrict__ ei, const float* __restrict__ dinv,
                                const int* __restrict__ rowptr, int* __restrict__ fill,
                                int* __restrict__ cols, float* __restrict__ vals, int E) {
  int e = blockIdx.x * blockDim.x + threadIdx.x;
  int stride = gridDim.x * blockDim.x;
  for (; e < E; e += stride) {
    int s = ei[e], t = ei[E + e];
    int pos = rowptr[t] + atomicAdd(&fill[t], 1);
    cols[pos] = s;
    vals[pos] = dinv[s] * dinv[t];
  }
}

// ---------------- propagation (CSR gather of fp16 rows, f32 accumulate) ----
// EPI: 0 none | 1 +bias(f32) | 2 relu(+bias f32) | 3 0.5*acc+0.5*bx16(fp16)
// OUT bits: 1 = f32 out | 2 = bf16 hi/lo splits | 4 = fp16 plane pf
template <int D, int EPI, int OUT>
__global__ __launch_bounds__(256) void prop_csr_kernel(
    const hf4* __restrict__ h, const int* __restrict__ rowptr,
    const int* __restrict__ cols, const float* __restrict__ vals,
    const float* __restrict__ dinv, const float* __restrict__ bias,
    const hf4* __restrict__ bx16,
    float4* __restrict__ out, ushort4* __restrict__ hi, ushort4* __restrict__ lo,
    hf4* __restrict__ pf, int N) {
  constexpr int TPN = D / 4;
  constexpr int NPB = 256 / TPN;
  const int node = blockIdx.x * NPB + threadIdx.x / TPN;
  const int q = threadIdx.x % TPN;
  if (node >= N) return;
  const int start = rowptr[node], end = rowptr[node + 1];
  float4 acc = make_float4(0.f, 0.f, 0.f, 0.f);
  int j = start;
  for (; j + 1 < end; j += 2) {
    const float v0 = vals[j], v1 = vals[j + 1];
    const hf4 a = h[(long long)cols[j] * TPN + q];
    const hf4 b = h[(long long)cols[j + 1] * TPN + q];
    acc.x += v0 * (float)a.x + v1 * (float)b.x;
    acc.y += v0 * (float)a.y + v1 * (float)b.y;
    acc.z += v0 * (float)a.z + v1 * (float)b.z;
    acc.w += v0 * (float)a.w + v1 * (float)b.w;
  }
  if (j < end) {
    const float v = vals[j];
    const hf4 a = h[(long long)cols[j] * TPN + q];
    acc.x += v * (float)a.x; acc.y += v * (float)a.y;
    acc.z += v * (float)a.z; acc.w += v * (float)a.w;
  }
  {
    const float di = dinv[node];
    const float sv = di * di;
    const hf4 a = h[(long long)node * TPN + q];
    acc.x += sv * (float)a.x; acc.y += sv * (float)a.y;
    acc.z += sv * (float)a.z; acc.w += sv * (float)a.w;
  }
  float4 r;
  if (EPI == 0) {
    r = acc;
  } else if (EPI == 1 || EPI == 2) {
    float4 b = ((const float4*)bias)[q];
    r.x = acc.x + b.x; r.y = acc.y + b.y; r.z = acc.z + b.z; r.w = acc.w + b.w;
    if (EPI == 2) {
      r.x = fmaxf(r.x, 0.f); r.y = fmaxf(r.y, 0.f);
      r.z = fmaxf(r.z, 0.f); r.w = fmaxf(r.w, 0.f);
    }
  } else {  // EPI == 3
    hf4 x0 = bx16[(long long)node * TPN + q];
    r.x = 0.5f * (acc.x + (float)x0.x); r.y = 0.5f * (acc.y + (float)x0.y);
    r.z = 0.5f * (acc.z + (float)x0.z); r.w = 0.5f * (acc.w + (float)x0.w);
  }
  const long long o = (long long)node * TPN + q;
  if (OUT & 1) out[o] = r;
  if (OUT & 2) {
    ushort4 h4, l4;
    h4.x = f32_to_bf16(r.x); l4.x = f32_to_bf16(r.x - bf16_to_f32(h4.x));
    h4.y = f32_to_bf16(r.y); l4.y = f32_to_bf16(r.y - bf16_to_f32(h4.y));
    h4.z = f32_to_bf16(r.z); l4.z = f32_to_bf16(r.z - bf16_to_f32(h4.z));
    h4.w = f32_to_bf16(r.w); l4.w = f32_to_bf16(r.w - bf16_to_f32(h4.w));
    hi[o] = h4;
    lo[o] = l4;
  }
  if (OUT & 4) {
    hf4 p;
    p.x = (_Float16)r.x; p.y = (_Float16)r.y;
    p.z = (_Float16)r.z; p.w = (_Float16)r.w;
    pf[o] = p;
  }
}

// ---------------- split-bf16 conversion (layer-4 pad only) ----------------
__global__ void conv_hilo_kernel(const float* __restrict__ in, unsigned short* __restrict__ hi,
                                 unsigned short* __restrict__ lo, int N, int K, int Kp) {
  const long long total = (long long)N * (Kp / 4);
  long long i = (long long)blockIdx.x * blockDim.x + threadIdx.x;
  const long long stride = (long long)gridDim.x * blockDim.x;
  const int q = Kp / 4;
  for (; i < total; i += stride) {
    int r = (int)(i / q);
    int col = (int)(i % q) * 4;
    ushort4 h4 = make_ushort4(0, 0, 0, 0), l4 = make_ushort4(0, 0, 0, 0);
    if (col < K) {
      float4 v = *(const float4*)(in + (long long)r * K + col);
      h4.x = f32_to_bf16(v.x); l4.x = f32_to_bf16(v.x - bf16_to_f32(h4.x));
      h4.y = f32_to_bf16(v.y); l4.y = f32_to_bf16(v.y - bf16_to_f32(h4.y));
      h4.z = f32_to_bf16(v.z); l4.z = f32_to_bf16(v.z - bf16_to_f32(h4.z));
      h4.w = f32_to_bf16(v.w); l4.w = f32_to_bf16(v.w - bf16_to_f32(h4.w));
    }
    *(ushort4*)(hi + (long long)r * Kp + col) = h4;
    *(ushort4*)(lo + (long long)r * Kp + col) = l4;
  }
}

// ---------------- weight packing (fragment order) ----------------
__global__ void pack_w_kernel(const float* __restrict__ W, unsigned short* __restrict__ hi,
                              unsigned short* __restrict__ lo, int K, int M) {
  int i = blockIdx.x * blockDim.x + threadIdx.x;
  int stride = gridDim.x * blockDim.x;
  const int MT = M >> 4;
  for (; i < K * M; i += stride) {
    int k = i / M, m = i % M;
    float v = W[i];
    unsigned short h = f32_to_bf16(v);
    unsigned short l = f32_to_bf16(v - bf16_to_f32(h));
    int chunk = k >> 6, kin = k & 63;
    int s = (kin >> 5) & 1, kin2 = kin & 31;
    int lane = ((kin2 >> 3) << 4) | (m & 15);
    int j = kin2 & 7, t = m >> 4;
    long long idx = ((((long long)(chunk * MT + t) * 2 + s) * 64 + lane) * 8 + j);
    hi[idx] = h;
    lo[idx] = l;
  }
}

// ---------------- MFMA GEMM (split-bf16, 3 products) ----------------
// EPI: 0 none | 2 bias+relu.  COUT: 0 = f32 direct | 1 = fp16 via LDS stage
template <int MT, int EPI, int COUT>
__global__ __launch_bounds__(256) void gemm_mfma_kernel(
    const unsigned short* __restrict__ Ahi, const unsigned short* __restrict__ Alo,
    const unsigned short* __restrict__ Phi, const unsigned short* __restrict__ Plo,
    const float* __restrict__ bias, float* __restrict__ C, _Float16* __restrict__ Pf,
    int N, int Kp) {
  constexpr int M = MT * 16;
  constexpr int chunk_elems = M * 64;
  __shared__ unsigned short lds[2 * chunk_elems];  // = 128*M ushorts
  const int tid = threadIdx.x;
  const int w = tid >> 6, l = tid & 63;
  const int lr = l & 15, lh = l >> 4;
  const int rowbase = blockIdx.x * 128 + w * 32;
  int r0 = rowbase + lr;      if (r0 >= N) r0 = N - 1;
  int r1 = rowbase + 16 + lr; if (r1 >= N) r1 = N - 1;

  f32x4 acc[2][MT] = {};
  unsigned short* ldsHi = lds;
  unsigned short* ldsLo = lds + chunk_elems;
  const int nchunks = Kp >> 6;
  const int n16 = chunk_elems / 8;

  for (int c = 0; c < nchunks; ++c) {
    const uint4* srcH = (const uint4*)(Phi + (long long)c * chunk_elems);
    const uint4* srcL = (const uint4*)(Plo + (long long)c * chunk_elems);
    uint4* dH = (uint4*)ldsHi;
    uint4* dL = (uint4*)ldsLo;
    __syncthreads();
    for (int i = tid; i < n16; i += 256) { dH[i] = srcH[i]; dL[i] = srcL[i]; }
    __syncthreads();
#pragma unroll
    for (int s = 0; s < 2; ++s) {
      const long long abase = (long long)c * 64 + s * 32 + lh * 8;
      short8 a0h = *(const short8*)(Ahi + (long long)r0 * Kp + abase);
      short8 a0l = *(const short8*)(Alo + (long long)r0 * Kp + abase);
      short8 a1h = *(const short8*)(Ahi + (long long)r1 * Kp + abase);
      short8 a1l = *(const short8*)(Alo + (long long)r1 * Kp + abase);
#pragma unroll
      for (int t = 0; t < MT; ++t) {
        const int boff = ((t * 2 + s) * 64 + l) * 8;
        short8 bh = *(const short8*)(ldsHi + boff);
        short8 bl = *(const short8*)(ldsLo + boff);
        acc[0][t] = __builtin_amdgcn_mfma_f32_16x16x32_bf16(a0h, bh, acc[0][t], 0, 0, 0);
        acc[0][t] = __builtin_amdgcn_mfma_f32_16x16x32_bf16(a0h, bl, acc[0][t], 0, 0, 0);
        acc[0][t] = __builtin_amdgcn_mfma_f32_16x16x32_bf16(a0l, bh, acc[0][t], 0, 0, 0);
        acc[1][t] = __builtin_amdgcn_mfma_f32_16x16x32_bf16(a1h, bh, acc[1][t], 0, 0, 0);
        acc[1][t] = __builtin_amdgcn_mfma_f32_16x16x32_bf16(a1h, bl, acc[1][t], 0, 0, 0);
        acc[1][t] = __builtin_amdgcn_mfma_f32_16x16x32_bf16(a1l, bh, acc[1][t], 0, 0, 0);
      }
    }
  }
  if (COUT == 0) {
#pragma unroll
    for (int rt = 0; rt < 2; ++rt) {
#pragma unroll
      for (int t = 0; t < MT; ++t) {
        const int col = t * 16 + lr;
        float b = (EPI == 2) ? bias[col] : 0.f;
#pragma unroll
        for (int j = 0; j < 4; ++j) {
          int row = rowbase + rt * 16 + lh * 4 + j;
          if (row < N) {
            float v = acc[rt][t][j] + b;
            if (EPI == 2) v = fmaxf(v, 0.f);
            C[(long long)row * M + col] = v;
          }
        }
      }
    }
  } else {
    // stage fp16 tile in LDS (done with B-staging), then coalesced 16B stores
    __syncthreads();
    _Float16* ldsH = (_Float16*)lds;
#pragma unroll
    for (int rt = 0; rt < 2; ++rt) {
#pragma unroll
      for (int t = 0; t < MT; ++t) {
        const int col = t * 16 + lr;
        float b = (EPI == 2) ? bias[col] : 0.f;
#pragma unroll
        for (int j = 0; j < 4; ++j) {
          float v = acc[rt][t][j] + b;
          if (EPI == 2) v = fmaxf(v, 0.f);
          ldsH[(w * 32 + rt * 16 + lh * 4 + j) * M + col] = (_Float16)v;
        }
      }
    }
    __syncthreads();
    constexpr int slots = 128 * M / 8;  // uint4 (8 halfs) per slot
    const uint4* ls = (const uint4*)lds;
    for (int i = tid; i < slots; i += 256) {
      int r = i / (M / 8);
      int c8 = i % (M / 8);
      int grow = blockIdx.x * 128 + r;
      if (grow < N) *(uint4*)(Pf + (long long)grow * M + c8 * 8) = ls[i];
    }
  }
}

// ---------------- fused GATv2 (online softmax, fp16 xl gather) -------------
__global__ __launch_bounds__(256) void gat_fused_kernel(
    const hf2* __restrict__ xl, const float2* __restrict__ xr,
    const float* __restrict__ att, const int* __restrict__ rowptr,
    const int* __restrict__ cols, const float* __restrict__ bg,
    hf2* __restrict__ outv, int N) {
  const int node = blockIdx.x * 4 + (threadIdx.x >> 6);
  if (node >= N) return;
  const int lane = threadIdx.x & 63;
  const float2 xrv = xr[(long long)node * 64 + lane];
  const float2 av = ((const float2*)att)[lane];
  float m = -1e30f, s = 0.f;
  float accx = 0.f, accy = 0.f;
  const int start = rowptr[node], end = rowptr[node + 1];
  for (int j = start; j <= end; ++j) {
    const int col = (j < end) ? cols[j] : node;   // j==end: self-loop
    const hf2 xh = xl[(long long)col * 64 + lane];
    const float xx = (float)xh.x, xy = (float)xh.y;
    float tx = xx + xrv.x, ty = xy + xrv.y;
    tx = tx >= 0.f ? tx : 0.2f * tx;
    ty = ty >= 0.f ? ty : 0.2f * ty;
    float dot = av.x * tx + av.y * ty;
    dot += __shfl_xor(dot, 1);
    dot += __shfl_xor(dot, 2);
    dot += __shfl_xor(dot, 4);
    dot += __shfl_xor(dot, 8);   // 16-lane head group reduce
    const float mn = fmaxf(m, dot);
    const float scale = __expf(m - mn);
    const float p = __expf(dot - mn);
    s = s * scale + p;
    accx = accx * scale + p * xx;
    accy = accy * scale + p * xy;
    m = mn;
  }
  const float inv = 1.0f / (s + 1e-16f);
  const float2 b = ((const float2*)bg)[lane];
  hf2 r;
  r.x = (_Float16)fmaxf(accx * inv + b.x, 0.f);
  r.y = (_Float16)fmaxf(accy * inv + b.y, 0.f);
  outv[(long long)node * 64 + lane] = r;
}

// fp16 = relu(c1*h + c2*t)
__global__ void combine_relu_f16_kernel(const float4* __restrict__ h, const float4* __restrict__ t,
                                        hf4* __restrict__ pf, float c1, float c2, long long n4) {
  long long i = (long long)blockIdx.x * blockDim.x + threadIdx.x;
  long long stride = (long long)gridDim.x * blockDim.x;
  for (; i < n4; i += stride) {
    float4 a = h[i], b = t[i];
    hf4 r;
    r.x = (_Float16)fmaxf(c1 * a.x + c2 * b.x, 0.f);
    r.y = (_Float16)fmaxf(c1 * a.y + c2 * b.y, 0.f);
    r.z = (_Float16)fmaxf(c1 * a.z + c2 * b.z, 0.f);
    r.w = (_Float16)fmaxf(c1 * a.w + c2 * b.w, 0.f);
    pf[i] = r;
  }
}

// hi/lo = split_bf16(relu(c1*h + c2*t))
__global__ void combine_relu_hilo_kernel(const float4* __restrict__ h, const float4* __restrict__ t,
                                         ushort4* __restrict__ hi, ushort4* __restrict__ lo,
                                         float c1, float c2, long long n4) {
  long long i = (long long)blockIdx.x * blockDim.x + threadIdx.x;
  long long stride = (long long)gridDim.x * blockDim.x;
  for (; i < n4; i += stride) {
    float4 a = h[i], b = t[i];
    float4 r;
    r.x = fmaxf(c1 * a.x + c2 * b.x, 0.f);
    r.y = fmaxf(c1 * a.y + c2 * b.y, 0.f);
    r.z = fmaxf(c1 * a.z + c2 * b.z, 0.f);
    r.w = fmaxf(c1 * a.w + c2 * b.w, 0.f);
    ushort4 h4, l4;
    h4.x = f32_to_bf16(r.x); l4.x = f32_to_bf16(r.x - bf16_to_f32(h4.x));
    h4.y = f32_to_bf16(r.y); l4.y = f32_to_bf16(r.y - bf16_to_f32(h4.y));
    h4.z = f32_to_bf16(r.z); l4.z = f32_to_bf16(r.z - bf16_to_f32(h4.z));
    h4.w = f32_to_bf16(r.w); l4.w = f32_to_bf16(r.w - bf16_to_f32(h4.w));
    hi[i] = h4;
    lo[i] = l4;
  }
}

// ---------------------------------------------------------------------------

extern "C" void kernel_launch(void* const* d_in, const int* in_sizes, int n_in,
                              void* d_out, int out_size, void* d_ws, size_t ws_size,
                              hipStream_t stream) {
  const float* x  = (const float*)d_in[0];
  const int*   ei = (const int*)d_in[1];
  const float* W1 = (const float*)d_in[2];  const float* b1 = (const float*)d_in[3];
  const float* W2 = (const float*)d_in[4];  const float* b2 = (const float*)d_in[5];
  const float* W3 = (const float*)d_in[6];  const float* b3 = (const float*)d_in[7];
  const float* W4 = (const float*)d_in[8];  const float* b4 = (const float*)d_in[9];
  const float* Wl = (const float*)d_in[10]; const float* Wr = (const float*)d_in[11];
  const float* att= (const float*)d_in[12]; const float* bg = (const float*)d_in[13];
  const float* Wc1= (const float*)d_in[14];
  const float* W5 = (const float*)d_in[15]; const float* b5 = (const float*)d_in[16];
  const float* Wc2= (const float*)d_in[17];
  const float* Wo = (const float*)d_in[18]; const float* bo = (const float*)d_in[19];

  const int N = in_sizes[0] / 300;
  const int E = in_sizes[1] / 2;
  float* out = (float*)d_out;

  const float BETA = 0.04879016416943205f;
  const float OMB  = 1.0f - BETA;

  // ---- workspace carve-up (~239 MiB) ----
  float* wsf = (float*)d_ws;
  auto alloc = [&](long long nelem) {
    float* p = wsf; wsf += (nelem + 3) & ~3LL; return p;
  };
  float* dinv   = alloc(N);
  int*   rowptr = (int*)alloc(N + 1);
  int*   cols   = (int*)alloc(E);
  float* vals   = alloc(E);
  hf4*   x1f    = (hf4*)alloc((long long)N * 128);   // N*256 halfs
  hf4*   x2f    = (hf4*)alloc((long long)N * 64);    // N*128 halfs
  float* bufA   = alloc((long long)N * 256);
  float* bufB   = alloc((long long)N * 256);
  _Float16* Pf  = (_Float16*)alloc((long long)N * 128);  // N*256 halfs
  int*   bsum   = (int*)alloc(64);
  unsigned short* Ahi = (unsigned short*)alloc((long long)N * 160);  // N*320 ushorts
  unsigned short* Alo = (unsigned short*)alloc((long long)N * 160);
  struct WDesc { const float* W; int K, M; };
  WDesc wd[10] = {{W1,300,256},{W2,256,128},{W3,128,64},{W4,64,32},{Wl,32,128},
                  {Wr,32,128},{Wc1,128,128},{W5,128,256},{Wc2,256,256},{Wo,256,128}};
  long long woff[10], wtot = 0;
  int wkp[10];
  for (int i = 0; i < 10; ++i) {
    wkp[i] = (wd[i].K + 63) & ~63;
    woff[i] = wtot;
    wtot += 2LL * wkp[i] * wd[i].M;
  }
  unsigned short* warena = (unsigned short*)alloc(wtot / 2 + 4);
  // overlays: deg/fill (setup only) on Ahi/Alo; Pg (GAT out) on bufB (dead interval)
  int* deg  = (int*)Ahi;
  int* fill = (int*)Alo;
  hf2* Pg   = (hf2*)bufB;

  const int gemm_grid = (N + 127) / 128;
  auto gemm = [&](int wi, const float* bias, float* C, _Float16* pf,
                  int MT, int epi, int cout) {
    const unsigned short* Phi = warena + woff[wi];
    const unsigned short* Plo = Phi + (long long)wkp[wi] * wd[wi].M;
#define GEMM_CASE(MM, EE, CC) \
    if (MT == MM && epi == EE && cout == CC) { \
      gemm_mfma_kernel<MM,EE,CC><<<gemm_grid, 256, 0, stream>>>( \
          Ahi, Alo, Phi, Plo, bias, C, pf, N, wkp[wi]); return; }
    GEMM_CASE(16,0,1) GEMM_CASE(8,0,1) GEMM_CASE(4,0,1) GEMM_CASE(2,0,1)
    GEMM_CASE(16,2,1) GEMM_CASE(8,0,0) GEMM_CASE(16,0,0)
#undef GEMM_CASE
  };

  // ---- weight packing (once per launch) ----
  hipMemsetAsync(warena, 0, (size_t)wtot * sizeof(unsigned short), stream);
  for (int i = 0; i < 10; ++i) {
    unsigned short* Phi = warena + woff[i];
    unsigned short* Plo = Phi + (long long)wkp[i] * wd[i].M;
    int total = wd[i].K * wd[i].M;
    pack_w_kernel<<<(total + 255) / 256, 256, 0, stream>>>(wd[i].W, Phi, Plo, wd[i].K, wd[i].M);
  }

  // ---- CSR build ----
  hipMemsetAsync(deg, 0, (size_t)N * sizeof(int), stream);
  hipMemsetAsync(fill, 0, (size_t)N * sizeof(int), stream);
  hipMemsetAsync(rowptr, 0, sizeof(int), stream);
  deg_kernel<<<2048, 256, 0, stream>>>(ei, deg, E);
  dinv_kernel<<<(N + 255) / 256, 256, 0, stream>>>(deg, dinv, N);
  {
    int nb = (N + 2047) / 2048;
    scan_block_kernel<<<nb, 256, 0, stream>>>(deg, rowptr + 1, bsum, N);
    scan_small_kernel<<<1, 64, 0, stream>>>(bsum, nb);
    scan_add_kernel<<<nb, 256, 0, stream>>>(rowptr + 1, bsum, N);
  }
  fill_csr_kernel<<<2048, 256, 0, stream>>>(ei, dinv, rowptr, fill, cols, vals, E);

  // conv of raw x (f32 input) -> split planes for GEMM1
  {
    long long total = (long long)N * 80;
    conv_hilo_kernel<<<4096, 256, 0, stream>>>(x, Ahi, Alo, N, 300, 320);
  }

  ushort4* hi4 = (ushort4*)Ahi;
  ushort4* lo4 = (ushort4*)Alo;
  const hf4* Pf4 = (const hf4*)Pf;

  // ---- layer 1: x1 = relu(prop(x@W1)+b1) -> splits + fp16 residual ----
  gemm(0, nullptr, nullptr, Pf, 16, 0, 1);
  prop_csr_kernel<256,2,6><<<(N + 3) / 4, 256, 0, stream>>>(
      Pf4, rowptr, cols, vals, dinv, b1, nullptr, nullptr, hi4, lo4, x1f, N);

  // ---- layer 2 ----
  gemm(1, nullptr, nullptr, Pf, 8, 0, 1);
  prop_csr_kernel<128,2,6><<<(N + 7) / 8, 256, 0, stream>>>(
      Pf4, rowptr, cols, vals, dinv, b2, nullptr, nullptr, hi4, lo4, x2f, N);

  // ---- layer 3: splits only ----
  gemm(2, nullptr, nullptr, Pf, 4, 0, 1);
  prop_csr_kernel<64,2,2><<<(N + 15) / 16, 256, 0, stream>>>(
      Pf4, rowptr, cols, vals, dinv, b3, nullptr, nullptr, hi4, lo4, nullptr, N);

  // ---- layer 4: f32 out -> pad-conv to splits ----
  gemm(3, nullptr, nullptr, Pf, 2, 0, 1);
  prop_csr_kernel<32,2,1><<<(N + 31) / 32, 256, 0, stream>>>(
      Pf4, rowptr, cols, vals, dinv, b4, nullptr, (float4*)bufB, nullptr, nullptr, nullptr, N);
  conv_hilo_kernel<<<4096, 256, 0, stream>>>(bufB, Ahi, Alo, N, 32, 64);

  // ---- GATv2 ----
  gemm(4, nullptr, nullptr, Pf, 8, 0, 1);     // xl (fp16) in Pf
  gemm(5, nullptr, bufA, nullptr, 8, 0, 0);   // xr (f32) in bufA
  gat_fused_kernel<<<(N + 3) / 4, 256, 0, stream>>>(
      (const hf2*)Pf, (const float2*)bufA, att, rowptr, cols, bg, Pg, N);
  // x3 (fp16, N x 128) in Pg (= bufB overlay)

  // ---- GCN2 #1: h = 0.5*prop(x3)+0.5*x2 -> f32 h + splits ----
  prop_csr_kernel<128,3,3><<<(N + 7) / 8, 256, 0, stream>>>(
      (const hf4*)Pg, rowptr, cols, vals, dinv, nullptr, x2f, (float4*)bufA, hi4, lo4, nullptr, N);
  gemm(6, nullptr, bufB, nullptr, 8, 0, 0);   // h@Wc1 (f32) in bufB (Pg dead)
  combine_relu_f16_kernel<<<4096, 256, 0, stream>>>(
      (const float4*)bufA, (const float4*)bufB, (hf4*)Pf, OMB, BETA, (long long)N * 32);
  // res (fp16) in Pf

  // ---- W5 layer: relu(prop(res)@W5+b5) ----
  prop_csr_kernel<128,0,2><<<(N + 7) / 8, 256, 0, stream>>>(
      Pf4, rowptr, cols, vals, dinv, nullptr, nullptr, nullptr, hi4, lo4, nullptr, N);
  gemm(7, b5, nullptr, Pf, 16, 2, 1);         // y5 (fp16, N x 256) in Pf

  // ---- GCN2 #2: h2 = 0.5*prop(y5)+0.5*x1 -> f32 h2 + splits ----
  prop_csr_kernel<256,3,3><<<(N + 3) / 4, 256, 0, stream>>>(
      Pf4, rowptr, cols, vals, dinv, nullptr, x1f, (float4*)bufA, hi4, lo4, nullptr, N);
  gemm(8, nullptr, bufB, nullptr, 16, 0, 0);  // h2@Wc2 (f32) in bufB
  combine_relu_hilo_kernel<<<4096, 256, 0, stream>>>(
      (const float4*)bufA, (const float4*)bufB, hi4, lo4, OMB, BETA, (long long)N * 64);

  // ---- final: prop(res2@Wo) + bo ----
  gemm(9, nullptr, nullptr, Pf, 8, 0, 1);     // G9 (fp16, N x 128) in Pf
  prop_csr_kernel<128,1,1><<<(N + 7) / 8, 256, 0, stream>>>(
      Pf4, rowptr, cols, vals, dinv, bo, nullptr, (float4*)out, nullptr, nullptr, nullptr, N);
}

// Round 9
// 817.386 us; speedup vs baseline: 1.5921x; 1.1681x over previous
//
#include <hip/hip_runtime.h>
#include <math.h>

// ---------------------------------------------------------------------------
// GraphAutoEncoder forward on MI355X. Round 9:
//   - GEMMs: f16 MFMA, 2-product weight split (Whi/Wlo fp16). A = stored
//     fp16 activations directly (no A planes, no bf16 splits anywhere).
//     First GEMM (f32 input x) uses 3-product with A hi/lo fp16 split.
//   - GAT: 4-edge batched online softmax (breaks the serial exp chain that
//     made round-8's kernel VALU/latency bound at 48% VALUBusy)
//   - all activations fp16 ping-pong (PA/PB/XH); f32 only at final output
// ---------------------------------------------------------------------------

typedef __attribute__((ext_vector_type(4))) float f32x4;
typedef _Float16 hf2 __attribute__((ext_vector_type(2)));
typedef _Float16 hf4 __attribute__((ext_vector_type(4)));
typedef _Float16 hf8 __attribute__((ext_vector_type(8)));

// ---------------- CSR build ----------------

__global__ void deg_kernel(const int* __restrict__ ei, int* __restrict__ deg, int E) {
  int i = blockIdx.x * blockDim.x + threadIdx.x;
  int stride = gridDim.x * blockDim.x;
  for (; i < E; i += stride) atomicAdd(&deg[ei[E + i]], 1);
}

__global__ void dinv_kernel(const int* __restrict__ deg, float* __restrict__ dinv, int N) {
  int i = blockIdx.x * blockDim.x + threadIdx.x;
  if (i < N) dinv[i] = rsqrtf((float)(deg[i] + 1));  // +1 self-loop
}

__global__ __launch_bounds__(256) void scan_block_kernel(const int* __restrict__ in,
                                                         int* __restrict__ out,
                                                         int* __restrict__ bsum, int n) {
  __shared__ int lds[256];
  const int base = blockIdx.x * 2048;
  const int tid = threadIdx.x;
  int v[8];
  int s = 0;
#pragma unroll
  for (int k = 0; k < 8; ++k) {
    int idx = base + tid * 8 + k;
    v[k] = (idx < n) ? in[idx] : 0;
    s += v[k];
  }
  lds[tid] = s;
  __syncthreads();
  for (int off = 1; off < 256; off <<= 1) {
    int t = (tid >= off) ? lds[tid - off] : 0;
    __syncthreads();
    lds[tid] += t;
    __syncthreads();
  }
  int run = (tid > 0) ? lds[tid - 1] : 0;
#pragma unroll
  for (int k = 0; k < 8; ++k) {
    int idx = base + tid * 8 + k;
    run += v[k];
    if (idx < n) out[idx] = run;
  }
  if (tid == 255) bsum[blockIdx.x] = lds[255];
}

__global__ void scan_small_kernel(int* bsum, int nb) {
  if (threadIdx.x == 0 && blockIdx.x == 0) {
    int run = 0;
    for (int i = 0; i < nb; ++i) { int t = bsum[i]; bsum[i] = run; run += t; }
  }
}

__global__ __launch_bounds__(256) void scan_add_kernel(int* __restrict__ out,
                                                       const int* __restrict__ bsum, int n) {
  int idx = blockIdx.x * 2048 + threadIdx.x;
  const int add = bsum[blockIdx.x];
#pragma unroll
  for (int k = 0; k < 8; ++k, idx += 256)
    if (idx < n) out[idx] += add;
}

__global__ void fill_csr_kernel(const int* __restrict__ ei, const float* __restrict__ dinv,
                                const int* __restrict__ rowptr, int* __restrict__ fill,
                                int* __restrict__ cols, float* __restrict__ vals, int E) {
  int e = blockIdx.x * blockDim.x + threadIdx.x;
  int stride = gridDim.x * blockDim.x;
  for (; e < E; e += stride) {
    int s = ei[e], t = ei[E + e];
    int pos = rowptr[t] + atomicAdd(&fill[t], 1);
    cols[pos] = s;
    vals[pos] = dinv[s] * dinv[t];
  }
}

// ---------------- propagation (CSR gather fp16, f32 accumulate) ------------
// EPI: 0 none | 1 +bias(f32) | 2 relu(+bias f32) | 3 0.5*acc+0.5*bx16
// OUT: 1 = f32 out | 4 = fp16 pf.   OS = output row stride in hf4 units.
template <int D, int EPI, int OUT, int OS>
__global__ __launch_bounds__(256) void prop_csr_kernel(
    const hf4* __restrict__ h, const int* __restrict__ rowptr,
    const int* __restrict__ cols, const float* __restrict__ vals,
    const float* __restrict__ dinv, const float* __restrict__ bias,
    const hf4* __restrict__ bx16,
    float4* __restrict__ out, hf4* __restrict__ pf, int N) {
  constexpr int TPN = D / 4;
  constexpr int NPB = 256 / TPN;
  const int node = blockIdx.x * NPB + threadIdx.x / TPN;
  const int q = threadIdx.x % TPN;
  if (node >= N) return;
  const int start = rowptr[node], end = rowptr[node + 1];
  float4 acc = make_float4(0.f, 0.f, 0.f, 0.f);
  int j = start;
  for (; j + 1 < end; j += 2) {
    const float v0 = vals[j], v1 = vals[j + 1];
    const hf4 a = h[(long long)cols[j] * TPN + q];
    const hf4 b = h[(long long)cols[j + 1] * TPN + q];
    acc.x += v0 * (float)a.x + v1 * (float)b.x;
    acc.y += v0 * (float)a.y + v1 * (float)b.y;
    acc.z += v0 * (float)a.z + v1 * (float)b.z;
    acc.w += v0 * (float)a.w + v1 * (float)b.w;
  }
  if (j < end) {
    const float v = vals[j];
    const hf4 a = h[(long long)cols[j] * TPN + q];
    acc.x += v * (float)a.x; acc.y += v * (float)a.y;
    acc.z += v * (float)a.z; acc.w += v * (float)a.w;
  }
  {
    const float di = dinv[node];
    const float sv = di * di;
    const hf4 a = h[(long long)node * TPN + q];
    acc.x += sv * (float)a.x; acc.y += sv * (float)a.y;
    acc.z += sv * (float)a.z; acc.w += sv * (float)a.w;
  }
  float4 r;
  if (EPI == 0) {
    r = acc;
  } else if (EPI == 1 || EPI == 2) {
    float4 b = ((const float4*)bias)[q];
    r.x = acc.x + b.x; r.y = acc.y + b.y; r.z = acc.z + b.z; r.w = acc.w + b.w;
    if (EPI == 2) {
      r.x = fmaxf(r.x, 0.f); r.y = fmaxf(r.y, 0.f);
      r.z = fmaxf(r.z, 0.f); r.w = fmaxf(r.w, 0.f);
    }
  } else {  // EPI == 3
    hf4 x0 = bx16[(long long)node * TPN + q];
    r.x = 0.5f * (acc.x + (float)x0.x); r.y = 0.5f * (acc.y + (float)x0.y);
    r.z = 0.5f * (acc.z + (float)x0.z); r.w = 0.5f * (acc.w + (float)x0.w);
  }
  if (OUT == 1) {
    out[(long long)node * TPN + q] = r;
  } else {
    hf4 p;
    p.x = (_Float16)r.x; p.y = (_Float16)r.y;
    p.z = (_Float16)r.z; p.w = (_Float16)r.w;
    pf[(long long)node * OS + q] = p;
  }
}

// ---------------- x -> fp16 hi/lo planes (first GEMM only) -----------------
__global__ void conv_x_kernel(const float* __restrict__ in, hf4* __restrict__ hi,
                              hf4* __restrict__ lo, int N, int K, int Kp) {
  const long long total = (long long)N * (Kp / 4);
  long long i = (long long)blockIdx.x * blockDim.x + threadIdx.x;
  const long long stride = (long long)gridDim.x * blockDim.x;
  const int q = Kp / 4;
  for (; i < total; i += stride) {
    int r = (int)(i / q);
    int col = (int)(i % q) * 4;
    hf4 h4 = {0, 0, 0, 0}, l4 = {0, 0, 0, 0};
    if (col < K) {
      float4 v = *(const float4*)(in + (long long)r * K + col);
      h4.x = (_Float16)v.x; l4.x = (_Float16)(v.x - (float)h4.x);
      h4.y = (_Float16)v.y; l4.y = (_Float16)(v.y - (float)h4.y);
      h4.z = (_Float16)v.z; l4.z = (_Float16)(v.z - (float)h4.z);
      h4.w = (_Float16)v.w; l4.w = (_Float16)(v.w - (float)h4.w);
    }
    hi[(long long)r * q + (col / 4)] = h4;
    lo[(long long)r * q + (col / 4)] = l4;
  }
}

// ---------------- weight packing (fp16 hi/lo, fragment order) --------------
// lane l holds B[k = 64*chunk + 32*s + 8*(l>>4) + j][col = 16*t + (l&15)]
__global__ void pack_w_kernel(const float* __restrict__ W, _Float16* __restrict__ hi,
                              _Float16* __restrict__ lo, int K, int M) {
  int i = blockIdx.x * blockDim.x + threadIdx.x;
  int stride = gridDim.x * blockDim.x;
  const int MT = M >> 4;
  for (; i < K * M; i += stride) {
    int k = i / M, m = i % M;
    float v = W[i];
    _Float16 h = (_Float16)v;
    _Float16 l = (_Float16)(v - (float)h);
    int chunk = k >> 6, kin = k & 63;
    int s = (kin >> 5) & 1, kin2 = kin & 31;
    int lane = ((kin2 >> 3) << 4) | (m & 15);
    int j = kin2 & 7, t = m >> 4;
    long long idx = ((((long long)(chunk * MT + t) * 2 + s) * 64 + lane) * 8 + j);
    hi[idx] = h;
    lo[idx] = l;
  }
}

// ---------------- MFMA GEMM (f16, 2-product; ASPLIT=1 -> 3-product) --------
// EPI: 0 none | 2 bias+relu.  Output fp16 via LDS stage, coalesced stores.
template <int MT, int EPI, int ASPLIT>
__global__ __launch_bounds__(256) void gemm_mfma_kernel(
    const _Float16* __restrict__ A, const _Float16* __restrict__ Al,
    const _Float16* __restrict__ Bhi, const _Float16* __restrict__ Blo,
    const float* __restrict__ bias, _Float16* __restrict__ Cf, int N, int Kp) {
  constexpr int M = MT * 16;
  constexpr int chunk = M * 64;
  __shared__ _Float16 lds[2 * chunk];
  const int tid = threadIdx.x;
  const int w = tid >> 6, l = tid & 63;
  const int lr = l & 15, lh = l >> 4;
  const int rowbase = blockIdx.x * 128 + w * 32;
  int r0 = rowbase + lr;      if (r0 >= N) r0 = N - 1;
  int r1 = rowbase + 16 + lr; if (r1 >= N) r1 = N - 1;

  f32x4 acc[2][MT] = {};
  _Float16* ldsHi = lds;
  _Float16* ldsLo = lds + chunk;
  const int nchunks = Kp >> 6;
  const int n16 = chunk / 8;

  for (int c = 0; c < nchunks; ++c) {
    const uint4* srcH = (const uint4*)(Bhi + (long long)c * chunk);
    const uint4* srcL = (const uint4*)(Blo + (long long)c * chunk);
    __syncthreads();
    for (int i = tid; i < n16; i += 256) {
      ((uint4*)ldsHi)[i] = srcH[i];
      ((uint4*)ldsLo)[i] = srcL[i];
    }
    __syncthreads();
#pragma unroll
    for (int s = 0; s < 2; ++s) {
      const long long abase = (long long)c * 64 + s * 32 + lh * 8;
      hf8 a0 = *(const hf8*)(A + (long long)r0 * Kp + abase);
      hf8 a1 = *(const hf8*)(A + (long long)r1 * Kp + abase);
      hf8 a0l, a1l;
      if (ASPLIT) {
        a0l = *(const hf8*)(Al + (long long)r0 * Kp + abase);
        a1l = *(const hf8*)(Al + (long long)r1 * Kp + abase);
      }
#pragma unroll
      for (int t = 0; t < MT; ++t) {
        const int boff = ((t * 2 + s) * 64 + l) * 8;
        hf8 bh = *(const hf8*)(ldsHi + boff);
        hf8 bl = *(const hf8*)(ldsLo + boff);
        acc[0][t] = __builtin_amdgcn_mfma_f32_16x16x32_f16(a0, bh, acc[0][t], 0, 0, 0);
        acc[0][t] = __builtin_amdgcn_mfma_f32_16x16x32_f16(a0, bl, acc[0][t], 0, 0, 0);
        acc[1][t] = __builtin_amdgcn_mfma_f32_16x16x32_f16(a1, bh, acc[1][t], 0, 0, 0);
        acc[1][t] = __builtin_amdgcn_mfma_f32_16x16x32_f16(a1, bl, acc[1][t], 0, 0, 0);
        if (ASPLIT) {
          acc[0][t] = __builtin_amdgcn_mfma_f32_16x16x32_f16(a0l, bh, acc[0][t], 0, 0, 0);
          acc[1][t] = __builtin_amdgcn_mfma_f32_16x16x32_f16(a1l, bh, acc[1][t], 0, 0, 0);
        }
      }
    }
  }
  // epilogue: stage fp16 tile in LDS, then coalesced 16B stores
  __syncthreads();
#pragma unroll
  for (int rt = 0; rt < 2; ++rt) {
#pragma unroll
    for (int t = 0; t < MT; ++t) {
      const int col = t * 16 + lr;
      float b = (EPI == 2) ? bias[col] : 0.f;
#pragma unroll
      for (int j = 0; j < 4; ++j) {
        float v = acc[rt][t][j] + b;
        if (EPI == 2) v = fmaxf(v, 0.f);
        lds[(w * 32 + rt * 16 + lh * 4 + j) * M + col] = (_Float16)v;
      }
    }
  }
  __syncthreads();
  constexpr int slots = 128 * M / 8;
  const uint4* ls = (const uint4*)lds;
  for (int i = tid; i < slots; i += 256) {
    int r = i / (M / 8);
    int c8 = i % (M / 8);
    int grow = blockIdx.x * 128 + r;
    if (grow < N) *(uint4*)(Cf + (long long)grow * M + c8 * 8) = ls[i];
  }
}

// ---------------- fused GATv2 (online softmax, 4-edge batch) ---------------
// wave per node; lane owns dims {2*lane, 2*lane+1}; head = lane>>4.
__global__ __launch_bounds__(256) void gat_fused_kernel(
    const hf2* __restrict__ xl, const hf2* __restrict__ xr,
    const float* __restrict__ att, const int* __restrict__ rowptr,
    const int* __restrict__ cols, const float* __restrict__ bg,
    hf2* __restrict__ outv, int N) {
  const int node = blockIdx.x * 4 + (threadIdx.x >> 6);
  if (node >= N) return;
  const int lane = threadIdx.x & 63;
  const hf2 xrh = xr[(long long)node * 64 + lane];
  const float xrx = (float)xrh.x, xry = (float)xrh.y;
  const float2 av = ((const float2*)att)[lane];
  float m = -1e30f, s = 0.f;
  float accx = 0.f, accy = 0.f;
  const int start = rowptr[node];
  const int cnt = rowptr[node + 1] - start;
  const int items = cnt + 1;  // + self
  int i = 0;
  for (; i + 3 < items; i += 4) {
    float dx[4], dy[4], d[4];
#pragma unroll
    for (int k = 0; k < 4; ++k) {
      const int idx = i + k;
      const int col = (idx < cnt) ? cols[start + idx] : node;
      const hf2 xh = xl[(long long)col * 64 + lane];
      const float xx = (float)xh.x, xy = (float)xh.y;
      float tx = xx + xrx, ty = xy + xry;
      tx = tx >= 0.f ? tx : 0.2f * tx;
      ty = ty >= 0.f ? ty : 0.2f * ty;
      d[k] = av.x * tx + av.y * ty;
      dx[k] = xx; dy[k] = xy;
    }
#pragma unroll
    for (int k = 0; k < 4; ++k) {
      d[k] += __shfl_xor(d[k], 1);
      d[k] += __shfl_xor(d[k], 2);
      d[k] += __shfl_xor(d[k], 4);
      d[k] += __shfl_xor(d[k], 8);
    }
    const float mn = fmaxf(fmaxf(fmaxf(d[0], d[1]), fmaxf(d[2], d[3])), m);
    const float scale = __expf(m - mn);
    const float p0 = __expf(d[0] - mn), p1 = __expf(d[1] - mn);
    const float p2 = __expf(d[2] - mn), p3 = __expf(d[3] - mn);
    s = s * scale + ((p0 + p1) + (p2 + p3));
    accx = accx * scale + ((p0 * dx[0] + p1 * dx[1]) + (p2 * dx[2] + p3 * dx[3]));
    accy = accy * scale + ((p0 * dy[0] + p1 * dy[1]) + (p2 * dy[2] + p3 * dy[3]));
    m = mn;
  }
  for (; i < items; ++i) {
    const int col = (i < cnt) ? cols[start + i] : node;
    const hf2 xh = xl[(long long)col * 64 + lane];
    const float xx = (float)xh.x, xy = (float)xh.y;
    float tx = xx + xrx, ty = xy + xry;
    tx = tx >= 0.f ? tx : 0.2f * tx;
    ty = ty >= 0.f ? ty : 0.2f * ty;
    float dot = av.x * tx + av.y * ty;
    dot += __shfl_xor(dot, 1);
    dot += __shfl_xor(dot, 2);
    dot += __shfl_xor(dot, 4);
    dot += __shfl_xor(dot, 8);
    const float mn = fmaxf(m, dot);
    const float scale = __expf(m - mn);
    const float p = __expf(dot - mn);
    s = s * scale + p;
    accx = accx * scale + p * xx;
    accy = accy * scale + p * xy;
    m = mn;
  }
  const float inv = 1.0f / (s + 1e-16f);
  const float2 b = ((const float2*)bg)[lane];
  hf2 r;
  r.x = (_Float16)fmaxf(accx * inv + b.x, 0.f);
  r.y = (_Float16)fmaxf(accy * inv + b.y, 0.f);
  outv[(long long)node * 64 + lane] = r;
}

// fp16 = relu(c1*h + c2*t)  (hf8 vectorized)
__global__ void combine_relu_f16_kernel(const hf8* __restrict__ h, const hf8* __restrict__ t,
                                        hf8* __restrict__ o, float c1, float c2, long long n8) {
  long long i = (long long)blockIdx.x * blockDim.x + threadIdx.x;
  long long stride = (long long)gridDim.x * blockDim.x;
  for (; i < n8; i += stride) {
    hf8 a = h[i], b = t[i], r;
#pragma unroll
    for (int k = 0; k < 8; ++k)
      r[k] = (_Float16)fmaxf(c1 * (float)a[k] + c2 * (float)b[k], 0.f);
    o[i] = r;
  }
}

// ---------------------------------------------------------------------------

extern "C" void kernel_launch(void* const* d_in, const int* in_sizes, int n_in,
                              void* d_out, int out_size, void* d_ws, size_t ws_size,
                              hipStream_t stream) {
  const float* x  = (const float*)d_in[0];
  const int*   ei = (const int*)d_in[1];
  const float* W1 = (const float*)d_in[2];  const float* b1 = (const float*)d_in[3];
  const float* W2 = (const float*)d_in[4];  const float* b2 = (const float*)d_in[5];
  const float* W3 = (const float*)d_in[6];  const float* b3 = (const float*)d_in[7];
  const float* W4 = (const float*)d_in[8];  const float* b4 = (const float*)d_in[9];
  const float* Wl = (const float*)d_in[10]; const float* Wr = (const float*)d_in[11];
  const float* att= (const float*)d_in[12]; const float* bg = (const float*)d_in[13];
  const float* Wc1= (const float*)d_in[14];
  const float* W5 = (const float*)d_in[15]; const float* b5 = (const float*)d_in[16];
  const float* Wc2= (const float*)d_in[17];
  const float* Wo = (const float*)d_in[18]; const float* bo = (const float*)d_in[19];

  const int N = in_sizes[0] / 300;
  const int E = in_sizes[1] / 2;
  float* out = (float*)d_out;

  const float BETA = 0.04879016416943205f;
  const float OMB  = 1.0f - BETA;

  // ---- workspace carve-up (~165 MiB) ----
  float* wsf = (float*)d_ws;
  auto alloc = [&](long long nelem) {  // nelem in f32 units
    float* p = wsf; wsf += (nelem + 3) & ~3LL; return p;
  };
  float* dinv   = alloc(N);
  int*   rowptr = (int*)alloc(N + 1);
  int*   cols   = (int*)alloc(E);
  float* vals   = alloc(E);
  _Float16* x1f = (_Float16*)alloc((long long)N * 128);  // N*256 halfs
  _Float16* x2f = (_Float16*)alloc((long long)N * 64);   // N*128 halfs
  _Float16* XH  = (_Float16*)alloc((long long)N * 160);  // N*320 halfs
  _Float16* XL  = (_Float16*)alloc((long long)N * 160);
  _Float16* PA  = (_Float16*)alloc((long long)N * 128);  // N*256 halfs
  _Float16* PB  = (_Float16*)alloc((long long)N * 128);
  int*   bsum   = (int*)alloc(64);
  struct WDesc { const float* W; int K, M; };
  WDesc wd[10] = {{W1,300,256},{W2,256,128},{W3,128,64},{W4,64,32},{Wl,32,128},
                  {Wr,32,128},{Wc1,128,128},{W5,128,256},{Wc2,256,256},{Wo,256,128}};
  long long woff[10], wtot = 0;
  int wkp[10];
  for (int i = 0; i < 10; ++i) {
    wkp[i] = (wd[i].K + 63) & ~63;
    woff[i] = wtot;
    wtot += 2LL * wkp[i] * wd[i].M;    // hi+lo planes, halfs
  }
  _Float16* warena = (_Float16*)alloc(wtot / 2 + 4);
  // setup-only overlays (CSR build precedes any PA/PB use):
  int* deg  = (int*)PA;
  int* fill = (int*)PB;

  const int gemm_grid = (N + 127) / 128;
  auto gemm = [&](int wi, const _Float16* A, const _Float16* Al, const float* bias,
                  _Float16* C, int MT, int epi, int asplit) {
    const _Float16* Bhi = warena + woff[wi];
    const _Float16* Blo = Bhi + (long long)wkp[wi] * wd[wi].M;
#define GEMM_CASE(MM, EE, AA) \
    if (MT == MM && epi == EE && asplit == AA) { \
      gemm_mfma_kernel<MM,EE,AA><<<gemm_grid, 256, 0, stream>>>( \
          A, Al, Bhi, Blo, bias, C, N, wkp[wi]); return; }
    GEMM_CASE(16,0,1)
    GEMM_CASE(16,0,0) GEMM_CASE(16,2,0)
    GEMM_CASE(8,0,0)  GEMM_CASE(4,0,0) GEMM_CASE(2,0,0)
#undef GEMM_CASE
  };

  // ---- weight packing (once per launch) ----
  hipMemsetAsync(warena, 0, (size_t)wtot * sizeof(_Float16), stream);
  for (int i = 0; i < 10; ++i) {
    _Float16* Bhi = warena + woff[i];
    _Float16* Blo = Bhi + (long long)wkp[i] * wd[i].M;
    int total = wd[i].K * wd[i].M;
    pack_w_kernel<<<(total + 255) / 256, 256, 0, stream>>>(wd[i].W, Bhi, Blo, wd[i].K, wd[i].M);
  }

  // ---- CSR build (deg/fill overlay PA/PB) ----
  hipMemsetAsync(deg, 0, (size_t)N * sizeof(int), stream);
  hipMemsetAsync(fill, 0, (size_t)N * sizeof(int), stream);
  hipMemsetAsync(rowptr, 0, sizeof(int), stream);
  deg_kernel<<<2048, 256, 0, stream>>>(ei, deg, E);
  dinv_kernel<<<(N + 255) / 256, 256, 0, stream>>>(deg, dinv, N);
  {
    int nb = (N + 2047) / 2048;
    scan_block_kernel<<<nb, 256, 0, stream>>>(deg, rowptr + 1, bsum, N);
    scan_small_kernel<<<1, 64, 0, stream>>>(bsum, nb);
    scan_add_kernel<<<nb, 256, 0, stream>>>(rowptr + 1, bsum, N);
  }
  fill_csr_kernel<<<2048, 256, 0, stream>>>(ei, dinv, rowptr, fill, cols, vals, E);

  // ---- x -> fp16 hi/lo (first GEMM input) ----
  conv_x_kernel<<<4096, 256, 0, stream>>>(x, (hf4*)XH, (hf4*)XL, N, 300, 320);

  // ---- layer 1: x1 = relu(prop(x@W1)+b1) -> x1f ----
  gemm(0, XH, XL, nullptr, PA, 16, 0, 1);
  prop_csr_kernel<256,2,4,64><<<(N + 3) / 4, 256, 0, stream>>>(
      (const hf4*)PA, rowptr, cols, vals, dinv, b1, nullptr, nullptr, (hf4*)x1f, N);

  // ---- layer 2: x2f ----
  gemm(1, x1f, nullptr, nullptr, PA, 8, 0, 0);
  prop_csr_kernel<128,2,4,32><<<(N + 7) / 8, 256, 0, stream>>>(
      (const hf4*)PA, rowptr, cols, vals, dinv, b2, nullptr, nullptr, (hf4*)x2f, N);

  // ---- layer 3 ----
  gemm(2, x2f, nullptr, nullptr, PA, 4, 0, 0);
  prop_csr_kernel<64,2,4,16><<<(N + 15) / 16, 256, 0, stream>>>(
      (const hf4*)PA, rowptr, cols, vals, dinv, b3, nullptr, nullptr, (hf4*)PB, N);

  // ---- layer 4: output zero-padded to N x 64 for next GEMM (Kp=64) ----
  gemm(3, PB, nullptr, nullptr, PA, 2, 0, 0);
  hipMemsetAsync(PB, 0, (size_t)N * 64 * sizeof(_Float16), stream);
  prop_csr_kernel<32,2,4,16><<<(N + 31) / 32, 256, 0, stream>>>(
      (const hf4*)PA, rowptr, cols, vals, dinv, b4, nullptr, nullptr, (hf4*)PB, N);

  // ---- GATv2 ----
  gemm(4, PB, nullptr, nullptr, PA, 8, 0, 0);   // xl in PA
  gemm(5, PB, nullptr, nullptr, XH, 8, 0, 0);   // xr in XH
  gat_fused_kernel<<<(N + 3) / 4, 256, 0, stream>>>(
      (const hf2*)PA, (const hf2*)XH, att, rowptr, cols, bg, (hf2*)PB, N);
  // x3 (fp16 N x 128) in PB

  // ---- GCN2 #1: h = 0.5*prop(x3)+0.5*x2f -> PA; res = relu(OMB*h+BETA*h@Wc1) ----
  prop_csr_kernel<128,3,4,32><<<(N + 7) / 8, 256, 0, stream>>>(
      (const hf4*)PB, rowptr, cols, vals, dinv, nullptr, (const hf4*)x2f, nullptr, (hf4*)PA, N);
  gemm(6, PA, nullptr, nullptr, XH, 8, 0, 0);   // h@Wc1 in XH
  combine_relu_f16_kernel<<<2048, 256, 0, stream>>>(
      (const hf8*)PA, (const hf8*)XH, (hf8*)PB, OMB, BETA, (long long)N * 16);
  // res in PB

  // ---- W5 layer: relu(prop(res)@W5+b5) ----
  prop_csr_kernel<128,0,4,32><<<(N + 7) / 8, 256, 0, stream>>>(
      (const hf4*)PB, rowptr, cols, vals, dinv, nullptr, nullptr, nullptr, (hf4*)PA, N);
  gemm(7, PA, nullptr, b5, PB, 16, 2, 0);       // y5 (N x 256) in PB

  // ---- GCN2 #2: h2 = 0.5*prop(y5)+0.5*x1f -> PA; res2 = relu(OMB*h2+BETA*h2@Wc2) ----
  prop_csr_kernel<256,3,4,64><<<(N + 3) / 4, 256, 0, stream>>>(
      (const hf4*)PB, rowptr, cols, vals, dinv, nullptr, (const hf4*)x1f, nullptr, (hf4*)PA, N);
  gemm(8, PA, nullptr, nullptr, XH, 16, 0, 0);  // h2@Wc2 in XH
  combine_relu_f16_kernel<<<2048, 256, 0, stream>>>(
      (const hf8*)PA, (const hf8*)XH, (hf8*)PB, OMB, BETA, (long long)N * 32);
  // res2 (N x 256) in PB

  // ---- final: prop(res2@Wo) + bo -> f32 out ----
  gemm(9, PB, nullptr, nullptr, PA, 8, 0, 0);   // (N x 128) in PA
  prop_csr_kernel<128,1,1,32><<<(N + 7) / 8, 256, 0, stream>>>(
      (const hf4*)PA, rowptr, cols, vals, dinv, bo, nullptr, (float4*)out, nullptr, N);
}